// Round 3
// baseline (5930.268 us; speedup 1.0000x reference)
//
#include <hip/hip_runtime.h>
#include <math.h>

// Pad: insert 4 words after every 32 words -> keeps 16B alignment for b128
// reads while shifting banks per 32-block.
#define PAD(i) ((i) + (((i) >> 5) << 2))

// softplus = max(x,0) + log(1+exp(-|x|)); v_exp/v_log based, abs err ~1e-7
__device__ __forceinline__ float softplus_f(float x) {
    return fmaxf(x, 0.f) + __logf(1.f + __expf(-fabsf(x)));
}
// tanh = sign(x) * (1-e)/(1+e), e = exp(-2|x|)
__device__ __forceinline__ float tanh_f(float x) {
    float ax = fabsf(x);
    float e  = __expf(-2.f * ax);
    float r  = (1.f - e) * __builtin_amdgcn_rcpf(1.f + e);
    return copysignf(r, x);
}

__global__ __launch_bounds__(512, 2)
void ncde_kernel(const float* __restrict__ ts,
                 const float* __restrict__ cd,
                 const float* __restrict__ cc,
                 const float* __restrict__ cb,
                 const float* __restrict__ ca,
                 const float* __restrict__ iw0, const float* __restrict__ ib0,
                 const float* __restrict__ iw1, const float* __restrict__ ib1,
                 const float* __restrict__ iw2, const float* __restrict__ ib2,
                 const float* __restrict__ fw0, const float* __restrict__ fb0,
                 const float* __restrict__ fw1, const float* __restrict__ fb1,
                 const float* __restrict__ fw2, const float* __restrict__ fb2,
                 const float* __restrict__ lw, const float* __restrict__ lb,
                 float* __restrict__ out, int T)
{
    const int b   = blockIdx.x;
    const int t   = threadIdx.x;
    const int w4  = t >> 2;      // output index for layers 0/1 (4 threads per output)
    const int j4  = t & 3;       // k-slice index within the 4-thread group
    const int dd  = t & 7;       // data index for the einsum (layer 2)
    const int hh  = t >> 3;      // hidden index for the einsum group
    const int Tm1 = T - 1;

    __shared__ __align__(16) float ytmp[68];   // stage input y (PAD(63)=67)
    __shared__ __align__(16) float h1s[140];   // width activations (PAD(127)=139)
    __shared__ __align__(16) float h2s[140];
    __shared__ __align__(16) float dcb[24];    // d[0:8], c[8:16], b[16:24]
    __shared__ float xin[8];
    __shared__ float hs_s[1024];               // precomputed step sizes

    for (int i = t; i < Tm1; i += 512) hs_s[i] = ts[i + 1] - ts[i];

    // ---- register-resident vector-field weights ----
    float w0r[16], w1r[32], w2r[128];
    {
        const float4* p0 = (const float4*)(fw0 + (size_t)w4 * 64 + j4 * 16);
        #pragma unroll
        for (int q = 0; q < 4; ++q) ((float4*)w0r)[q] = p0[q];
        const float4* p1 = (const float4*)(fw1 + (size_t)w4 * 128 + j4 * 32);
        #pragma unroll
        for (int q = 0; q < 8; ++q) ((float4*)w1r)[q] = p1[q];
        const float4* p2 = (const float4*)(fw2 + (size_t)t * 128);
        #pragma unroll
        for (int q = 0; q < 32; ++q) ((float4*)w2r)[q] = p2[q];
    }
    const float fb0r = fb0[w4];
    const float fb1r = fb1[w4];
    const float fb2r = fb2[t];

    // ---- initial MLP: x = coeff_a[b,0,:]  (relu, relu, identity) ----
    if (t < 8) xin[t] = ca[((size_t)b * Tm1) * 8 + t];
    __syncthreads();

    if (t < 128) {                       // D(8) -> W(128)
        float a = ib0[t];
        #pragma unroll
        for (int k = 0; k < 8; ++k) a += iw0[t * 8 + k] * xin[k];
        h1s[PAD(t)] = fmaxf(a, 0.f);
    }
    __syncthreads();

    {                                    // W -> W
        const float* wrow = iw1 + (size_t)w4 * 128 + j4 * 32;
        const int base = j4 * 36;
        float a = 0.f;
        #pragma unroll
        for (int k = 0; k < 32; ++k) a += wrow[k] * h1s[base + k];
        a += __shfl_xor(a, 1); a += __shfl_xor(a, 2);
        if (j4 == 0) h2s[PAD(w4)] = fmaxf(a + ib1[w4], 0.f);
    }
    __syncthreads();

    if (t < 256) {                       // W -> H(64)
        const float* wrow = iw2 + (size_t)w4 * 128 + j4 * 32;
        const int base = j4 * 36;
        float a = 0.f;
        #pragma unroll
        for (int k = 0; k < 32; ++k) a += wrow[k] * h2s[base + k];
        a += __shfl_xor(a, 1); a += __shfl_xor(a, 2);
        if (j4 == 0) ytmp[PAD(w4)] = a + ib2[w4];
    }
    __syncthreads();

    // RK4 state in registers, replicated across each 8-lane einsum group
    float yy_r   = ytmp[PAD(hh)];
    float ksum_r = 0.f;

    const int b0 = j4 * 16 + ((j4 >> 1) << 2);   // PAD'ed slice base, layer 0
    const int b1 = j4 * 36;                      // PAD'ed slice base, layer 1

    // Prefetch interval-0 spline coefficients (consumed at stage 0, written
    // to LDS after the L0 barrier; next interval's load is issued there too,
    // giving ~4 stages (~4000 cyc) of latency cover).
    float4 dcbv = {0.f, 0.f, 0.f, 0.f};
    if (t < 6) {
        const float* p = (t < 2) ? cd : ((t < 4) ? cc : cb);
        dcbv = ((const float4*)(p + ((size_t)b * Tm1) * 8))[t & 1];
    }

    // ---- time loop: RK4 over T-1 intervals ----
    for (int i = 0; i < Tm1; ++i) {
        const float hstep = hs_s[i];

        #pragma unroll
        for (int st = 0; st < 4; ++st) {
            const float s = (st == 0) ? 0.f : ((st == 3) ? hstep : 0.5f * hstep);

            // ---- layer 0: y(64) -> w(128), softplus ----
            {
                float a0 = 0.f, a1 = 0.f;
                #pragma unroll
                for (int q = 0; q < 4; ++q) {
                    float4 y4 = ((const float4*)(ytmp + b0))[q];
                    a0 += w0r[4 * q]     * y4.x;
                    a1 += w0r[4 * q + 1] * y4.y;
                    a0 += w0r[4 * q + 2] * y4.z;
                    a1 += w0r[4 * q + 3] * y4.w;
                }
                float a = a0 + a1;
                a += __shfl_xor(a, 1); a += __shfl_xor(a, 2);
                if (j4 == 0) h1s[PAD(w4)] = softplus_f(a + fb0r);
            }
            __syncthreads();

            if (st == 0 && t < 6) {
                // publish interval i's coefficients (read first at L2 of this
                // stage, i.e. after the next barrier) ...
                ((float4*)dcb)[t] = dcbv;
                // ... and issue interval i+1's load (guard the last interval).
                const size_t nbase =
                    ((size_t)b * Tm1 + ((i + 1 < Tm1) ? (i + 1) : 0)) * 8;
                const float* p = (t < 2) ? cd : ((t < 4) ? cc : cb);
                dcbv = ((const float4*)(p + nbase))[t & 1];
            }

            // ---- layer 1: w(128) -> w(128), softplus ----
            {
                float a0 = 0.f, a1 = 0.f, a2 = 0.f, a3 = 0.f;
                #pragma unroll
                for (int q = 0; q < 8; ++q) {
                    float4 h4 = ((const float4*)(h1s + b1))[q];
                    a0 += w1r[4 * q]     * h4.x;
                    a1 += w1r[4 * q + 1] * h4.y;
                    a2 += w1r[4 * q + 2] * h4.z;
                    a3 += w1r[4 * q + 3] * h4.w;
                }
                float a = (a0 + a1) + (a2 + a3);
                a += __shfl_xor(a, 1); a += __shfl_xor(a, 2);
                if (j4 == 0) h2s[PAD(w4)] = softplus_f(a + fb1r);
            }
            __syncthreads();

            // ---- layer 2: w(128) -> 512, tanh, einsum with dX, RK4 update ----
            {
                float a0 = 0.f, a1 = 0.f, a2 = 0.f, a3 = 0.f;
                #pragma unroll
                for (int q = 0; q < 32; ++q) {
                    float4 h4 = *(const float4*)&h2s[4 * q + ((q >> 3) << 2)];
                    a0 += w2r[4 * q]     * h4.x;
                    a1 += w2r[4 * q + 1] * h4.y;
                    a2 += w2r[4 * q + 2] * h4.z;
                    a3 += w2r[4 * q + 3] * h4.w;
                }
                float g = tanh_f(((a0 + a1) + (a2 + a3)) + fb2r);
                // dX = (3 d s + 2 c) s + b for this thread's data index
                float dX = (3.f * dcb[dd] * s + 2.f * dcb[8 + dd]) * s + dcb[16 + dd];
                float pr = g * dX;
                pr += __shfl_xor(pr, 1); pr += __shfl_xor(pr, 2); pr += __shfl_xor(pr, 4);
                // pr == k[hh] on all 8 lanes of the group; update replicated state
                float ynext;
                if (st == 0)      { ksum_r  = pr;        ynext = yy_r + 0.5f * hstep * pr; }
                else if (st == 1) { ksum_r += 2.f * pr;  ynext = yy_r + 0.5f * hstep * pr; }
                else if (st == 2) { ksum_r += 2.f * pr;  ynext = yy_r + hstep * pr; }
                else              { yy_r += (hstep * (1.f / 6.f)) * (ksum_r + pr); ynext = yy_r; }
                if (dd == 0) ytmp[PAD(hh)] = ynext;
            }
            __syncthreads();
        }
    }

    // ---- readout: sigmoid(y . lw + lb) ----
    if (t < 64) {
        float v = ytmp[PAD(t)] * lw[t];
        #pragma unroll
        for (int off = 1; off < 64; off <<= 1) v += __shfl_xor(v, off);
        if (t == 0) out[b] = 1.f / (1.f + __expf(-(v + lb[0])));
    }
}

extern "C" void kernel_launch(void* const* d_in, const int* in_sizes, int n_in,
                              void* d_out, int out_size, void* d_ws, size_t ws_size,
                              hipStream_t stream) {
    const float* ts  = (const float*)d_in[0];
    const float* cd  = (const float*)d_in[1];
    const float* cc  = (const float*)d_in[2];
    const float* cb  = (const float*)d_in[3];
    const float* ca  = (const float*)d_in[4];
    const float* iw0 = (const float*)d_in[5];
    const float* ib0 = (const float*)d_in[6];
    const float* iw1 = (const float*)d_in[7];
    const float* ib1 = (const float*)d_in[8];
    const float* iw2 = (const float*)d_in[9];
    const float* ib2 = (const float*)d_in[10];
    const float* fw0 = (const float*)d_in[11];
    const float* fb0 = (const float*)d_in[12];
    const float* fw1 = (const float*)d_in[13];
    const float* fb1 = (const float*)d_in[14];
    const float* fw2 = (const float*)d_in[15];
    const float* fb2 = (const float*)d_in[16];
    const float* lw  = (const float*)d_in[17];
    const float* lb  = (const float*)d_in[18];
    float* out = (float*)d_out;

    const int T = in_sizes[0];      // 1024
    const int B = out_size;         // 128

    ncde_kernel<<<B, 512, 0, stream>>>(ts, cd, cc, cb, ca,
                                       iw0, ib0, iw1, ib1, iw2, ib2,
                                       fw0, fb0, fw1, fb1, fw2, fb2,
                                       lw, lb, out, T);
}